// Round 8
// baseline (299.491 us; speedup 1.0000x reference)
//
#include <hip/hip_runtime.h>
#include <hip/hip_bf16.h>
#include <hip/hip_fp16.h>

#define BB 32
#define TT 256
#define MM 16
#define DD 128
#define HH 128

typedef unsigned int uint;
typedef unsigned short ushort;

typedef _Float16 f16;
typedef _Float16 f16x8 __attribute__((ext_vector_type(8)));
typedef float f32x4 __attribute__((ext_vector_type(4)));

__device__ __forceinline__ float bl16(uint u){ return __uint_as_float(u << 16); }
__device__ __forceinline__ float bh16(uint u){ return __uint_as_float(u & 0xffff0000u); }

__device__ __forceinline__ float hsig(float x){
  // clamp(0.2x+0.5, 0, 1) via v_med3_f32
  return __builtin_amdgcn_fmed3f(fmaf(x, 0.2f, 0.5f), 0.0f, 1.0f);
}
__device__ __forceinline__ float tanh_f(float x){
  return 1.0f - 2.0f / (__expf(2.0f * x) + 1.0f);   // saturates correctly
}
__device__ __forceinline__ uint packh2(float a, float b){
  __half2 hv = __floats2half2_rn(a, b);
  union{__half2 h; uint x;} cv; cv.h = hv; return cv.x;
}
// quad_perm butterfly: all 4 quad lanes end with the quad sum
__device__ __forceinline__ float qsum4(float v){
  float t1 = __int_as_float(__builtin_amdgcn_mov_dpp(__float_as_int(v), 0xB1, 0xf, 0xf, true));
  v += t1;
  float t2 = __int_as_float(__builtin_amdgcn_mov_dpp(__float_as_int(v), 0x4E, 0xf, 0xf, true));
  return v + t2;
}

// ===================================================================================
// R8: revert to the R5 4-launch structure (R7 refuted both "merge" theories: the
// 32-CU xproj prologue cost +20us and the non-k_rec residual is ~105us FIXED harness
// overhead, invariant from 5 launches down to 1 — launch count is not the lever).
// Only change vs R5: k_rec runs 4 waves (256 thr, 1 wave/SIMD, waves_per_eu(1,1))
// instead of 8. Counter arithmetic said the two co-resident lockstep waves per SIMD
// SERIALIZE their issue phases (matrix 155cyc + VALU 175cyc per step per SIMD);
// 1 wave/SIMD keeps matrix time constant (32 MFMA/wave on 4 SIMDs) but halves
// per-SIMD VALU and removes 2-wave phase serialization + halves barrier skew.
// ===================================================================================

// ---------------- K_prep: fused {dtype probe + U-pack + W-pack + vx/flag} -----------
__global__ __launch_bounds__(256) void k_prep(
  const void* __restrict__ xraw, const void* __restrict__ Wa,
  const void* __restrict__ U0, const void* __restrict__ U1,
  const void* __restrict__ U2, const void* __restrict__ U3,
  const void* __restrict__ W0, const void* __restrict__ W1,
  const void* __restrict__ W2, const void* __restrict__ W3,
  int* __restrict__ flag, float* __restrict__ vx,
  uint4* __restrict__ Uw, uint4* __restrict__ Ww)
{
  __shared__ int cnt[256];
  __shared__ int smode;
  int tid = threadIdx.x;
  int bid = blockIdx.x;
  {
    const ushort* u = (const ushort*)xraw;
    int c = 0;
    #pragma unroll
    for (int j = 0; j < 8; ++j){
      ushort v = u[2 * (tid * 8 + j)];
      float f = __uint_as_float(((uint)v) << 16);
      if (f == f && fabsf(f) < 64.f && fabsf(f) > 1e-12f) ++c;
    }
    cnt[tid] = c;
    __syncthreads();
    if (tid == 0){
      int s = 0;
      for (int i = 0; i < 256; ++i) s += cnt[i];
      smode = (s > 1024) ? 1 : 0;
    }
    __syncthreads();
  }
  int mode = smode;

  if (bid < 64){
    // frag f=(g*4+kc)*8+cb; lane l, elem e: M[k][c], k=kc*32+(l>>4)*8+e, c=cb*16+(l&15)
    int idx = (bid & 31) * 256 + tid;
    int f = idx >> 6, lane = idx & 63;
    int g = f >> 5, kc = (f >> 3) & 3, cb = f & 7;
    int k0 = kc * 32 + (lane >> 4) * 8;
    int c  = cb * 16 + (lane & 15);
    const void* Ms[4];
    if (bid < 32){ Ms[0] = U0; Ms[1] = U1; Ms[2] = U2; Ms[3] = U3; }
    else         { Ms[0] = W0; Ms[1] = W1; Ms[2] = W2; Ms[3] = W3; }
    float v[8];
    if (mode){
      const ushort* U = (const ushort*)Ms[g];
      #pragma unroll
      for (int e = 0; e < 8; ++e)
        v[e] = __uint_as_float(((uint)U[(size_t)(k0 + e) * HH + c]) << 16);
    } else {
      const float* U = (const float*)Ms[g];
      #pragma unroll
      for (int e = 0; e < 8; ++e)
        v[e] = U[(size_t)(k0 + e) * HH + c];
    }
    uint4 o;
    o.x = packh2(v[0], v[1]); o.y = packh2(v[2], v[3]);
    o.z = packh2(v[4], v[5]); o.w = packh2(v[6], v[7]);
    ((bid < 32) ? Uw : Ww)[idx] = o;
  } else {
    if (tid == 0) *flag = mode;
    if (tid < 128){
      int d = tid;
      float s = 0.f;
      if (mode){
        const uint4* row = (const uint4*)((const ushort*)Wa + d * HH);
        #pragma unroll
        for (int q = 0; q < 16; ++q){
          uint4 v = row[q];
          s += bl16(v.x) + bh16(v.x) + bl16(v.y) + bh16(v.y)
             + bl16(v.z) + bh16(v.z) + bl16(v.w) + bh16(v.w);
        }
      } else {
        const float4* row = (const float4*)((const float*)Wa + d * HH);
        #pragma unroll
        for (int q = 0; q < 32; ++q){
          float4 v = row[q];
          s += v.x + v.y + v.z + v.w;
        }
      }
      vx[d] = s;
    }
  }
}

// ---------------- K1: softmax-pool, 2 (b,t)-tiles per block (f16 out) ---------------
__global__ __launch_bounds__(256) void k_pool(const void* __restrict__ xraw,
                                              const int* __restrict__ flag,
                                              const float* __restrict__ vx,
                                              __half* __restrict__ newx){
  __shared__ float xs[2][MM][DD];
  __shared__ float sc[2][MM];
  int mode = *flag;
  int tid = threadIdx.x;
  int half = tid >> 7, t2 = tid & 127;
  int bt = blockIdx.x * 2 + half;
  int b = bt >> 8, t = bt & 255;

  float* xdst = &xs[half][0][0];
  if (mode){
    const float* vxp = vx + (t2 & 15) * 8;
    float4 vra = *(const float4*)vxp;
    float4 vrb = *(const float4*)(vxp + 4);
    const uint4* s = (const uint4*)((const ushort*)xraw + (size_t)bt * 2048);
    float sq[2];
    #pragma unroll
    for (int q = 0; q < 2; ++q){
      int ch = t2 + 128 * q;
      uint4 v = s[ch];
      float* d = &xdst[ch * 8];
      float e0 = bl16(v.x), e1 = bh16(v.x), e2 = bl16(v.y), e3 = bh16(v.y);
      float e4 = bl16(v.z), e5 = bh16(v.z), e6 = bl16(v.w), e7 = bh16(v.w);
      d[0] = e0; d[1] = e1; d[2] = e2; d[3] = e3;
      d[4] = e4; d[5] = e5; d[6] = e6; d[7] = e7;
      float p = e0 * vra.x;
      p = fmaf(e1, vra.y, p); p = fmaf(e2, vra.z, p); p = fmaf(e3, vra.w, p);
      p = fmaf(e4, vrb.x, p); p = fmaf(e5, vrb.y, p); p = fmaf(e6, vrb.z, p);
      p = fmaf(e7, vrb.w, p);
      sq[q] = p;
    }
    #pragma unroll
    for (int q = 0; q < 2; ++q){
      float v = qsum4(sq[q]);
      v += __shfl_xor(v, 4, 16);
      v += __shfl_xor(v, 8, 16);
      sq[q] = v;
    }
    if ((t2 & 15) == 0){
      sc[half][t2 >> 4]       = sq[0];
      sc[half][(t2 >> 4) + 8] = sq[1];
    }
  } else {
    float4 vra = *(const float4*)(vx + (t2 & 31) * 4);
    const float4* s = (const float4*)((const float*)xraw + (size_t)bt * 2048);
    float sq[4];
    #pragma unroll
    for (int q = 0; q < 4; ++q){
      int ch = t2 + 128 * q;
      float4 v = s[ch];
      *(float4*)&xdst[ch * 4] = v;
      float p = v.x * vra.x;
      p = fmaf(v.y, vra.y, p); p = fmaf(v.z, vra.z, p); p = fmaf(v.w, vra.w, p);
      sq[q] = p;
    }
    #pragma unroll
    for (int q = 0; q < 4; ++q){
      float v = qsum4(sq[q]);
      v += __shfl_xor(v, 4, 32);
      v += __shfl_xor(v, 8, 32);
      v += __shfl_xor(v, 16, 32);
      sq[q] = v;
    }
    if ((t2 & 31) == 0){
      int mb = t2 >> 5;
      sc[half][mb]      = sq[0];
      sc[half][mb + 4]  = sq[1];
      sc[half][mb + 8]  = sq[2];
      sc[half][mb + 12] = sq[3];
    }
  }
  __syncthreads();

  float mx = sc[half][0];
  #pragma unroll
  for (int m2 = 1; m2 < MM; ++m2) mx = fmaxf(mx, sc[half][m2]);
  float wgt[MM]; float den = 0.f;
  #pragma unroll
  for (int m2 = 0; m2 < MM; ++m2){ wgt[m2] = __expf(sc[half][m2] - mx); den += wgt[m2]; }
  float inv = 1.0f / den;

  float acc = 0.f;
  #pragma unroll
  for (int m2 = 0; m2 < MM; ++m2)
    acc = fmaf(wgt[m2], xs[half][m2][t2], acc);
  newx[((size_t)t * BB + b) * DD + t2] = __float2half(acc * inv);
}

// ---------------- K2: MFMA x-projection (R4/R5, verified) ---------------------------
__global__ __launch_bounds__(256) void k_xproj(const __half* __restrict__ nx,
  const uint4* __restrict__ Ww,
  const void* __restrict__ b0_, const void* __restrict__ b1_,
  const void* __restrict__ b2_, const void* __restrict__ b3_,
  const int* __restrict__ flag, float* __restrict__ Xp)
{
  __shared__ __align__(16) char As[32768];
  int tid = threadIdx.x;
  int r0 = blockIdx.x * 128;
  int G  = blockIdx.y;
  int lane = tid & 63, w = tid >> 6;
  int l16 = lane & 15, lq = lane >> 4;

  {
    const uint4* src = (const uint4*)(nx + (size_t)r0 * DD);
    uint4* dst = (uint4*)As;
    #pragma unroll
    for (int i = 0; i < 8; ++i){
      int gid = i * 256 + tid;
      int r = gid >> 4, c16 = gid & 15;
      dst[r * 16 + (c16 ^ (r & 15))] = src[gid];
    }
  }

  int mode = *flag;
  const void* bb = (G == 0) ? b0_ : (G == 1) ? b1_ : (G == 2) ? b2_ : b3_;
  float bias[8];
  #pragma unroll
  for (int cb = 0; cb < 8; ++cb){
    int col = cb * 16 + l16;
    bias[cb] = mode ? __uint_as_float(((uint)((const ushort*)bb)[col]) << 16)
                    : ((const float*)bb)[col];
  }
  __syncthreads();

  int rb = w * 32;
  f32x4 acc[2][8];
  #pragma unroll
  for (int mt = 0; mt < 2; ++mt)
    #pragma unroll
    for (int cb = 0; cb < 8; ++cb)
      acc[mt][cb] = (f32x4){bias[cb], bias[cb], bias[cb], bias[cb]};

  #pragma unroll
  for (int kc = 0; kc < 4; ++kc){
    f16x8 a[2];
    #pragma unroll
    for (int mt = 0; mt < 2; ++mt){
      int r = rb + mt * 16 + l16;
      int g16 = (kc * 4 + lq) ^ (r & 15);
      a[mt] = *(const f16x8*)(As + r * 256 + g16 * 16);
    }
    #pragma unroll
    for (int cb = 0; cb < 8; ++cb){
      union{uint4 u; f16x8 h;} bv;
      bv.u = Ww[((size_t)((G * 4 + kc) * 8 + cb)) * 64 + lane];
      acc[0][cb] = __builtin_amdgcn_mfma_f32_16x16x32_f16(a[0], bv.h, acc[0][cb], 0, 0, 0);
      acc[1][cb] = __builtin_amdgcn_mfma_f32_16x16x32_f16(a[1], bv.h, acc[1][cb], 0, 0, 0);
    }
  }

  #pragma unroll
  for (int mt = 0; mt < 2; ++mt)
    #pragma unroll
    for (int cb = 0; cb < 8; ++cb)
      #pragma unroll
      for (int reg = 0; reg < 4; ++reg){
        size_t r = (size_t)(r0 + rb + mt * 16 + lq * 4 + reg);
        Xp[r * 512 + G * HH + cb * 16 + l16] = acc[mt][cb][reg];
      }
}

// ---------------- K3: recurrence, 4 waves (1 wave/SIMD) -----------------------------
// Wave wv owns cols [wv*32, wv*32+32) for all 4 gates: 2 col-blocks (cb) x 4 gates
// x depth-2 chains = 32 MFMA/wave/step (same 128/block/step as R5, now 32 on each
// of 4 SIMDs instead of 2x16 on each). Ub doubles to 32 frags (128 VGPR) — fine at
// waves_per_eu(1,1). Accumulator arrays are fully-unrolled const-indexed (rule #20).
__global__ __attribute__((amdgpu_waves_per_eu(1, 1))) __launch_bounds__(256)
void k_rec(const float* __restrict__ Xp, const uint4* __restrict__ Uw,
           float* __restrict__ out)
{
  __shared__ __align__(16) __half hlds[2][HH];   // 512 B double-buffered h
  int tid  = threadIdx.x;
  int b    = blockIdx.x;
  int wv   = tid >> 6;          // wave id: cols wv*32 .. wv*32+31
  int lane = tid & 63;
  int l16  = lane & 15, lq = lane >> 4;

  // ---- B-frags: Ub[cb][g*4+kc], cb = col-block 0/1 -> frag col index wv*2+cb ----
  f16x8 Ub[2][16];
  #pragma unroll
  for (int cb = 0; cb < 2; ++cb)
    #pragma unroll
    for (int g = 0; g < 4; ++g)
      #pragma unroll
      for (int kc = 0; kc < 4; ++kc){
        uint4 v = Uw[((g * 4 + kc) * 8 + wv * 2 + cb) * 64 + lane];
        union{uint4 u; f16x8 h;} cv; cv.u = v;
        Ub[cb][g * 4 + kc] = cv.h;
      }

  // ---- per-thread Xp pointers; prime t=0,1. xp[g*2+cb] ----
  const float* xcol = Xp + (size_t)b * 512 + wv * 32 + l16;
  float xpA[8], xpB[8];
  #pragma unroll
  for (int g = 0; g < 4; ++g)
    #pragma unroll
    for (int cb = 0; cb < 2; ++cb){
      xpA[g * 2 + cb] = xcol[g * 128 + cb * 16];
      xpB[g * 2 + cb] = xcol[(size_t)(BB * 512) + g * 128 + cb * 16];
    }

  if (tid < 64) ((uint*)&hlds[0][0])[tid] = 0;   // h(0) = 0 (128 f16)
  float cst0 = 0.f, cst1 = 0.f, vh0 = 0.f, vh1 = 0.f;
  const int lo = lq * 16;                        // byte offset of lane's k-slice
  __syncthreads();

#define STEP(T, XP) do{                                                        \
    const char* hb = (const char*)&hlds[(T) & 1][0];                           \
    f16x8 a0 = *(const f16x8*)(hb +   0 + lo);                                 \
    f16x8 a1 = *(const f16x8*)(hb +  64 + lo);                                 \
    f16x8 a2 = *(const f16x8*)(hb + 128 + lo);                                 \
    f16x8 a3 = *(const f16x8*)(hb + 192 + lo);                                 \
    f32x4 cc[2][4], dd[2][4];                                                  \
    _Pragma("unroll")                                                          \
    for (int cb = 0; cb < 2; ++cb)                                             \
      _Pragma("unroll")                                                        \
      for (int g = 0; g < 4; ++g){ cc[cb][g][0] = XP[g * 2 + cb];              \
                                   dd[cb][g][0] = 0.f; }                       \
    _Pragma("unroll")                                                          \
    for (int cb = 0; cb < 2; ++cb)                                             \
      _Pragma("unroll")                                                        \
      for (int g = 0; g < 4; ++g){                                             \
        cc[cb][g] = __builtin_amdgcn_mfma_f32_16x16x32_f16(a0, Ub[cb][g*4+0],  \
                                                           cc[cb][g], 0,0,0); \
        dd[cb][g] = __builtin_amdgcn_mfma_f32_16x16x32_f16(a2, Ub[cb][g*4+2],  \
                                                           dd[cb][g], 0,0,0); \
      }                                                                        \
    _Pragma("unroll")                                                          \
    for (int cb = 0; cb < 2; ++cb)                                             \
      _Pragma("unroll")                                                        \
      for (int g = 0; g < 4; ++g){                                             \
        cc[cb][g] = __builtin_amdgcn_mfma_f32_16x16x32_f16(a1, Ub[cb][g*4+1],  \
                                                           cc[cb][g], 0,0,0); \
        dd[cb][g] = __builtin_amdgcn_mfma_f32_16x16x32_f16(a3, Ub[cb][g*4+3],  \
                                                           dd[cb][g], 0,0,0); \
      }                                                                        \
    {                                                                          \
      float p0 = cc[0][0][0] + dd[0][0][0];                                    \
      float p1 = cc[0][1][0] + dd[0][1][0];                                    \
      float p2 = cc[0][2][0] + dd[0][2][0];                                    \
      float p3 = cc[0][3][0] + dd[0][3][0];                                    \
      float ig = hsig(p0), fg = hsig(p1), og = hsig(p3);                       \
      float gg = tanh_f(p2);                                                   \
      cst0 = fmaf(fg, cst0, ig * gg);                                          \
      vh0  = og * tanh_f(cst0);                                                \
      p0 = cc[1][0][0] + dd[1][0][0];                                          \
      p1 = cc[1][1][0] + dd[1][1][0];                                          \
      p2 = cc[1][2][0] + dd[1][2][0];                                          \
      p3 = cc[1][3][0] + dd[1][3][0];                                          \
      ig = hsig(p0); fg = hsig(p1); og = hsig(p3);                             \
      gg = tanh_f(p2);                                                         \
      cst1 = fmaf(fg, cst1, ig * gg);                                          \
      vh1  = og * tanh_f(cst1);                                                \
    }                                                                          \
    if (lane < 16){                                                            \
      hlds[((T) + 1) & 1][wv * 32 + lane]      = __float2half(vh0);            \
      hlds[((T) + 1) & 1][wv * 32 + 16 + lane] = __float2half(vh1);            \
    }                                                                          \
    {                                                                          \
      int tp = (T) + 2; if (tp > TT - 1) tp = TT - 1;                          \
      const float* xsrc = xcol + ((size_t)tp << 14);                           \
      _Pragma("unroll")                                                        \
      for (int g = 0; g < 4; ++g)                                              \
        _Pragma("unroll")                                                      \
        for (int cb = 0; cb < 2; ++cb)                                         \
          XP[g * 2 + cb] = xsrc[g * 128 + cb * 16];                            \
    }                                                                          \
    asm volatile("s_waitcnt lgkmcnt(0)" ::: "memory");                         \
    __builtin_amdgcn_s_barrier();                                              \
    asm volatile("" ::: "memory");                                             \
  }while(0)

  for (int t = 0; t < TT; t += 2){
    STEP(t,     xpA);
    STEP(t + 1, xpB);
  }
#undef STEP

  if (lane < 16){
    out[b * HH + wv * 32 + lane]      = vh0;
    out[b * HH + wv * 32 + 16 + lane] = vh1;
  }
}

extern "C" void kernel_launch(void* const* d_in, const int* in_sizes, int n_in,
                              void* d_out, int out_size, void* d_ws, size_t ws_size,
                              hipStream_t stream) {
  (void)in_sizes; (void)n_in; (void)out_size; (void)ws_size;

  // ---- workspace layout (~18.4 MB) ----
  // [0,16) flag | [16,528) vx | [1024,+128K) Uw | [+128K) Ww | [+2M) newx | [+16M) Xp
  char* ws = (char*)d_ws;
  int* flag = (int*)ws;
  float* vx = (float*)(ws + 16);
  uint4* Uw = (uint4*)(ws + 1024);
  uint4* Ww = (uint4*)(ws + 1024 + 131072);
  __half* newx = (__half*)(ws + 1024 + 2 * 131072);
  float* Xp = (float*)(ws + 1024 + 2 * 131072 + (size_t)2 * 1024 * 1024);

  k_prep<<<65, 256, 0, stream>>>(d_in[0], d_in[1],
      d_in[4], d_in[7], d_in[10], d_in[13],    // U_i, U_f, U_c, U_o
      d_in[3], d_in[6], d_in[9],  d_in[12],    // W_i, W_f, W_c, W_o
      flag, vx, Uw, Ww);
  k_pool<<<BB * TT / 2, 256, 0, stream>>>(d_in[0], flag, vx, newx);
  dim3 g2(64, 4);
  k_xproj<<<g2, 256, 0, stream>>>(newx, Ww,
      d_in[5], d_in[8], d_in[11], d_in[14],    // b_i, b_f, b_c, b_o
      flag, Xp);
  k_rec<<<BB, 256, 0, stream>>>(Xp, Uw, (float*)d_out);
}

// Round 9
// 243.129 us; speedup vs baseline: 1.2318x; 1.2318x over previous
//
#include <hip/hip_runtime.h>
#include <hip/hip_bf16.h>
#include <hip/hip_fp16.h>

#define BB 32
#define TT 256
#define MM 16
#define DD 128
#define HH 128

typedef unsigned int uint;
typedef unsigned short ushort;

typedef _Float16 f16;
typedef _Float16 f16x8 __attribute__((ext_vector_type(8)));
typedef float f32x4 __attribute__((ext_vector_type(4)));

__device__ __forceinline__ float bl16(uint u){ return __uint_as_float(u << 16); }
__device__ __forceinline__ float bh16(uint u){ return __uint_as_float(u & 0xffff0000u); }

__device__ __forceinline__ float hsig(float x){
  // clamp(0.2x+0.5, 0, 1) via v_med3_f32
  return __builtin_amdgcn_fmed3f(fmaf(x, 0.2f, 0.5f), 0.0f, 1.0f);
}
// R9: Pade 7/8 tanh, input clamped to +-4.8. Max abs err ~1e-4 over all x
// (interior ~2e-5; saturated tail outputs 0.99995 vs 1.0). Mechanism: removes the
// dependent v_exp (trans pipe, serial chain) from both tanh's per step; num/den
// FMA trees evaluate in parallel; one v_rcp remains.
__device__ __forceinline__ float tanh_f(float x){
  x = __builtin_amdgcn_fmed3f(x, -4.8f, 4.8f);
  float x2 = x * x;
  float num = x * fmaf(x2, fmaf(x2, fmaf(x2, 1.0f, 378.0f), 17325.0f), 135135.0f);
  float den = fmaf(x2, fmaf(x2, fmaf(x2, 28.0f, 3150.0f), 62370.0f), 135135.0f);
  return num * __builtin_amdgcn_rcpf(den);
}
__device__ __forceinline__ uint packh2(float a, float b){
  __half2 hv = __floats2half2_rn(a, b);
  union{__half2 h; uint x;} cv; cv.h = hv; return cv.x;
}
// quad_perm butterfly: all 4 quad lanes end with the quad sum
__device__ __forceinline__ float qsum4(float v){
  float t1 = __int_as_float(__builtin_amdgcn_mov_dpp(__float_as_int(v), 0xB1, 0xf, 0xf, true));
  v += t1;
  float t2 = __int_as_float(__builtin_amdgcn_mov_dpp(__float_as_int(v), 0x4E, 0xf, 0xf, true));
  return v + t2;
}

// ===================================================================================
// R9: k_rec reverted to R4-exact (best measured, 121.4us: 8 waves / 2 per SIMD —
// R8 proved 1 wave/SIMD exposes all dep-chain latency, +42%), plus two trims:
//   (a) Pade tanh (above) — cuts 2 serial v_exp from the gate chain per step;
//   (b) prefetch clamp dropped — Xp gets a 128KB slack tail (2 rows), removing
//       1 cmp + 4 cndmask per step from the distance-2 prefetch.
// Upstream kernels are R5-exact (proven).
// ===================================================================================

// ---------------- K_prep: fused {dtype probe + U-pack + W-pack + vx/flag} -----------
__global__ __launch_bounds__(256) void k_prep(
  const void* __restrict__ xraw, const void* __restrict__ Wa,
  const void* __restrict__ U0, const void* __restrict__ U1,
  const void* __restrict__ U2, const void* __restrict__ U3,
  const void* __restrict__ W0, const void* __restrict__ W1,
  const void* __restrict__ W2, const void* __restrict__ W3,
  int* __restrict__ flag, float* __restrict__ vx,
  uint4* __restrict__ Uw, uint4* __restrict__ Ww)
{
  __shared__ int cnt[256];
  __shared__ int smode;
  int tid = threadIdx.x;
  int bid = blockIdx.x;
  {
    const ushort* u = (const ushort*)xraw;
    int c = 0;
    #pragma unroll
    for (int j = 0; j < 8; ++j){
      ushort v = u[2 * (tid * 8 + j)];
      float f = __uint_as_float(((uint)v) << 16);
      if (f == f && fabsf(f) < 64.f && fabsf(f) > 1e-12f) ++c;
    }
    cnt[tid] = c;
    __syncthreads();
    if (tid == 0){
      int s = 0;
      for (int i = 0; i < 256; ++i) s += cnt[i];
      smode = (s > 1024) ? 1 : 0;
    }
    __syncthreads();
  }
  int mode = smode;

  if (bid < 64){
    // frag f=(g*4+kc)*8+cb; lane l, elem e: M[k][c], k=kc*32+(l>>4)*8+e, c=cb*16+(l&15)
    int idx = (bid & 31) * 256 + tid;
    int f = idx >> 6, lane = idx & 63;
    int g = f >> 5, kc = (f >> 3) & 3, cb = f & 7;
    int k0 = kc * 32 + (lane >> 4) * 8;
    int c  = cb * 16 + (lane & 15);
    const void* Ms[4];
    if (bid < 32){ Ms[0] = U0; Ms[1] = U1; Ms[2] = U2; Ms[3] = U3; }
    else         { Ms[0] = W0; Ms[1] = W1; Ms[2] = W2; Ms[3] = W3; }
    float v[8];
    if (mode){
      const ushort* U = (const ushort*)Ms[g];
      #pragma unroll
      for (int e = 0; e < 8; ++e)
        v[e] = __uint_as_float(((uint)U[(size_t)(k0 + e) * HH + c]) << 16);
    } else {
      const float* U = (const float*)Ms[g];
      #pragma unroll
      for (int e = 0; e < 8; ++e)
        v[e] = U[(size_t)(k0 + e) * HH + c];
    }
    uint4 o;
    o.x = packh2(v[0], v[1]); o.y = packh2(v[2], v[3]);
    o.z = packh2(v[4], v[5]); o.w = packh2(v[6], v[7]);
    ((bid < 32) ? Uw : Ww)[idx] = o;
  } else {
    if (tid == 0) *flag = mode;
    if (tid < 128){
      int d = tid;
      float s = 0.f;
      if (mode){
        const uint4* row = (const uint4*)((const ushort*)Wa + d * HH);
        #pragma unroll
        for (int q = 0; q < 16; ++q){
          uint4 v = row[q];
          s += bl16(v.x) + bh16(v.x) + bl16(v.y) + bh16(v.y)
             + bl16(v.z) + bh16(v.z) + bl16(v.w) + bh16(v.w);
        }
      } else {
        const float4* row = (const float4*)((const float*)Wa + d * HH);
        #pragma unroll
        for (int q = 0; q < 32; ++q){
          float4 v = row[q];
          s += v.x + v.y + v.z + v.w;
        }
      }
      vx[d] = s;
    }
  }
}

// ---------------- K1: softmax-pool, 2 (b,t)-tiles per block (f16 out) ---------------
__global__ __launch_bounds__(256) void k_pool(const void* __restrict__ xraw,
                                              const int* __restrict__ flag,
                                              const float* __restrict__ vx,
                                              __half* __restrict__ newx){
  __shared__ float xs[2][MM][DD];
  __shared__ float sc[2][MM];
  int mode = *flag;
  int tid = threadIdx.x;
  int half = tid >> 7, t2 = tid & 127;
  int bt = blockIdx.x * 2 + half;
  int b = bt >> 8, t = bt & 255;

  float* xdst = &xs[half][0][0];
  if (mode){
    const float* vxp = vx + (t2 & 15) * 8;
    float4 vra = *(const float4*)vxp;
    float4 vrb = *(const float4*)(vxp + 4);
    const uint4* s = (const uint4*)((const ushort*)xraw + (size_t)bt * 2048);
    float sq[2];
    #pragma unroll
    for (int q = 0; q < 2; ++q){
      int ch = t2 + 128 * q;
      uint4 v = s[ch];
      float* d = &xdst[ch * 8];
      float e0 = bl16(v.x), e1 = bh16(v.x), e2 = bl16(v.y), e3 = bh16(v.y);
      float e4 = bl16(v.z), e5 = bh16(v.z), e6 = bl16(v.w), e7 = bh16(v.w);
      d[0] = e0; d[1] = e1; d[2] = e2; d[3] = e3;
      d[4] = e4; d[5] = e5; d[6] = e6; d[7] = e7;
      float p = e0 * vra.x;
      p = fmaf(e1, vra.y, p); p = fmaf(e2, vra.z, p); p = fmaf(e3, vra.w, p);
      p = fmaf(e4, vrb.x, p); p = fmaf(e5, vrb.y, p); p = fmaf(e6, vrb.z, p);
      p = fmaf(e7, vrb.w, p);
      sq[q] = p;
    }
    #pragma unroll
    for (int q = 0; q < 2; ++q){
      float v = qsum4(sq[q]);
      v += __shfl_xor(v, 4, 16);
      v += __shfl_xor(v, 8, 16);
      sq[q] = v;
    }
    if ((t2 & 15) == 0){
      sc[half][t2 >> 4]       = sq[0];
      sc[half][(t2 >> 4) + 8] = sq[1];
    }
  } else {
    float4 vra = *(const float4*)(vx + (t2 & 31) * 4);
    const float4* s = (const float4*)((const float*)xraw + (size_t)bt * 2048);
    float sq[4];
    #pragma unroll
    for (int q = 0; q < 4; ++q){
      int ch = t2 + 128 * q;
      float4 v = s[ch];
      *(float4*)&xdst[ch * 4] = v;
      float p = v.x * vra.x;
      p = fmaf(v.y, vra.y, p); p = fmaf(v.z, vra.z, p); p = fmaf(v.w, vra.w, p);
      sq[q] = p;
    }
    #pragma unroll
    for (int q = 0; q < 4; ++q){
      float v = qsum4(sq[q]);
      v += __shfl_xor(v, 4, 32);
      v += __shfl_xor(v, 8, 32);
      v += __shfl_xor(v, 16, 32);
      sq[q] = v;
    }
    if ((t2 & 31) == 0){
      int mb = t2 >> 5;
      sc[half][mb]      = sq[0];
      sc[half][mb + 4]  = sq[1];
      sc[half][mb + 8]  = sq[2];
      sc[half][mb + 12] = sq[3];
    }
  }
  __syncthreads();

  float mx = sc[half][0];
  #pragma unroll
  for (int m2 = 1; m2 < MM; ++m2) mx = fmaxf(mx, sc[half][m2]);
  float wgt[MM]; float den = 0.f;
  #pragma unroll
  for (int m2 = 0; m2 < MM; ++m2){ wgt[m2] = __expf(sc[half][m2] - mx); den += wgt[m2]; }
  float inv = 1.0f / den;

  float acc = 0.f;
  #pragma unroll
  for (int m2 = 0; m2 < MM; ++m2)
    acc = fmaf(wgt[m2], xs[half][m2][t2], acc);
  newx[((size_t)t * BB + b) * DD + t2] = __float2half(acc * inv);
}

// ---------------- K2: MFMA x-projection (R4/R5, verified) ---------------------------
__global__ __launch_bounds__(256) void k_xproj(const __half* __restrict__ nx,
  const uint4* __restrict__ Ww,
  const void* __restrict__ b0_, const void* __restrict__ b1_,
  const void* __restrict__ b2_, const void* __restrict__ b3_,
  const int* __restrict__ flag, float* __restrict__ Xp)
{
  __shared__ __align__(16) char As[32768];
  int tid = threadIdx.x;
  int r0 = blockIdx.x * 128;
  int G  = blockIdx.y;
  int lane = tid & 63, w = tid >> 6;
  int l16 = lane & 15, lq = lane >> 4;

  {
    const uint4* src = (const uint4*)(nx + (size_t)r0 * DD);
    uint4* dst = (uint4*)As;
    #pragma unroll
    for (int i = 0; i < 8; ++i){
      int gid = i * 256 + tid;
      int r = gid >> 4, c16 = gid & 15;
      dst[r * 16 + (c16 ^ (r & 15))] = src[gid];
    }
  }

  int mode = *flag;
  const void* bb = (G == 0) ? b0_ : (G == 1) ? b1_ : (G == 2) ? b2_ : b3_;
  float bias[8];
  #pragma unroll
  for (int cb = 0; cb < 8; ++cb){
    int col = cb * 16 + l16;
    bias[cb] = mode ? __uint_as_float(((uint)((const ushort*)bb)[col]) << 16)
                    : ((const float*)bb)[col];
  }
  __syncthreads();

  int rb = w * 32;
  f32x4 acc[2][8];
  #pragma unroll
  for (int mt = 0; mt < 2; ++mt)
    #pragma unroll
    for (int cb = 0; cb < 8; ++cb)
      acc[mt][cb] = (f32x4){bias[cb], bias[cb], bias[cb], bias[cb]};

  #pragma unroll
  for (int kc = 0; kc < 4; ++kc){
    f16x8 a[2];
    #pragma unroll
    for (int mt = 0; mt < 2; ++mt){
      int r = rb + mt * 16 + l16;
      int g16 = (kc * 4 + lq) ^ (r & 15);
      a[mt] = *(const f16x8*)(As + r * 256 + g16 * 16);
    }
    #pragma unroll
    for (int cb = 0; cb < 8; ++cb){
      union{uint4 u; f16x8 h;} bv;
      bv.u = Ww[((size_t)((G * 4 + kc) * 8 + cb)) * 64 + lane];
      acc[0][cb] = __builtin_amdgcn_mfma_f32_16x16x32_f16(a[0], bv.h, acc[0][cb], 0, 0, 0);
      acc[1][cb] = __builtin_amdgcn_mfma_f32_16x16x32_f16(a[1], bv.h, acc[1][cb], 0, 0, 0);
    }
  }

  #pragma unroll
  for (int mt = 0; mt < 2; ++mt)
    #pragma unroll
    for (int cb = 0; cb < 8; ++cb)
      #pragma unroll
      for (int reg = 0; reg < 4; ++reg){
        size_t r = (size_t)(r0 + rb + mt * 16 + lq * 4 + reg);
        Xp[r * 512 + G * HH + cb * 16 + l16] = acc[mt][cb][reg];
      }
}

// ---------------- K3: recurrence (R4-exact structure + pade tanh + no-clamp) --------
__global__ __attribute__((amdgpu_waves_per_eu(2, 2))) __launch_bounds__(512)
void k_rec(const float* __restrict__ Xp, const uint4* __restrict__ Uw,
           float* __restrict__ out)
{
  __shared__ __align__(16) __half hlds[2][HH];   // 512 B double-buffered h
  int tid  = threadIdx.x;
  int b    = blockIdx.x;
  int w    = tid >> 6;          // wave id: col block w*16..w*16+15
  int lane = tid & 63;
  int l16  = lane & 15;

  // ---- B-frags: Ub[g*4+kc], 16 coalesced dwordx4 loads ----
  f16x8 Ub[16];
  #pragma unroll
  for (int g = 0; g < 4; ++g)
    #pragma unroll
    for (int kc = 0; kc < 4; ++kc){
      uint4 v = Uw[((g * 4 + kc) * 8 + w) * 64 + lane];
      union{uint4 u; f16x8 h;} cv; cv.u = v;
      Ub[g * 4 + kc] = cv.h;
    }

  // ---- per-thread Xp column pointer; prime t=0,1 ----
  const float* xcol = Xp + (size_t)b * 512 + w * 16 + l16;
  float xpA[4], xpB[4];
  #pragma unroll
  for (int g = 0; g < 4; ++g) xpA[g] = xcol[g * 128];
  #pragma unroll
  for (int g = 0; g < 4; ++g) xpB[g] = xcol[(size_t)(BB * 512) + g * 128];

  if (tid < 64) ((uint*)&hlds[0][0])[tid] = 0;   // h(0) = 0 (128 f16)
  float cst = 0.f, vh = 0.f;
  const int lo = (lane >> 4) * 16;               // byte offset of lane's k-slice
  __syncthreads();

#define STEP(T, XP) do{                                                        \
    const char* hb = (const char*)&hlds[(T) & 1][0];                           \
    f16x8 a0 = *(const f16x8*)(hb +   0 + lo);                                 \
    f16x8 a1 = *(const f16x8*)(hb +  64 + lo);                                 \
    f16x8 a2 = *(const f16x8*)(hb + 128 + lo);                                 \
    f16x8 a3 = *(const f16x8*)(hb + 192 + lo);                                 \
    f32x4 c0 = {XP[0], XP[0], XP[0], XP[0]};                                   \
    f32x4 c1 = {XP[1], XP[1], XP[1], XP[1]};                                   \
    f32x4 c2 = {XP[2], XP[2], XP[2], XP[2]};                                   \
    f32x4 c3 = {XP[3], XP[3], XP[3], XP[3]};                                   \
    f32x4 d0 = {0.f, 0.f, 0.f, 0.f};                                           \
    f32x4 d1 = {0.f, 0.f, 0.f, 0.f};                                           \
    f32x4 d2 = {0.f, 0.f, 0.f, 0.f};                                           \
    f32x4 d3 = {0.f, 0.f, 0.f, 0.f};                                           \
    c0 = __builtin_amdgcn_mfma_f32_16x16x32_f16(a0, Ub[ 0], c0, 0, 0, 0);      \
    c1 = __builtin_amdgcn_mfma_f32_16x16x32_f16(a0, Ub[ 4], c1, 0, 0, 0);      \
    c2 = __builtin_amdgcn_mfma_f32_16x16x32_f16(a0, Ub[ 8], c2, 0, 0, 0);      \
    c3 = __builtin_amdgcn_mfma_f32_16x16x32_f16(a0, Ub[12], c3, 0, 0, 0);      \
    d0 = __builtin_amdgcn_mfma_f32_16x16x32_f16(a2, Ub[ 2], d0, 0, 0, 0);      \
    d1 = __builtin_amdgcn_mfma_f32_16x16x32_f16(a2, Ub[ 6], d1, 0, 0, 0);      \
    d2 = __builtin_amdgcn_mfma_f32_16x16x32_f16(a2, Ub[10], d2, 0, 0, 0);      \
    d3 = __builtin_amdgcn_mfma_f32_16x16x32_f16(a2, Ub[14], d3, 0, 0, 0);      \
    c0 = __builtin_amdgcn_mfma_f32_16x16x32_f16(a1, Ub[ 1], c0, 0, 0, 0);      \
    c1 = __builtin_amdgcn_mfma_f32_16x16x32_f16(a1, Ub[ 5], c1, 0, 0, 0);      \
    c2 = __builtin_amdgcn_mfma_f32_16x16x32_f16(a1, Ub[ 9], c2, 0, 0, 0);      \
    c3 = __builtin_amdgcn_mfma_f32_16x16x32_f16(a1, Ub[13], c3, 0, 0, 0);      \
    d0 = __builtin_amdgcn_mfma_f32_16x16x32_f16(a3, Ub[ 3], d0, 0, 0, 0);      \
    d1 = __builtin_amdgcn_mfma_f32_16x16x32_f16(a3, Ub[ 7], d1, 0, 0, 0);      \
    d2 = __builtin_amdgcn_mfma_f32_16x16x32_f16(a3, Ub[11], d2, 0, 0, 0);      \
    d3 = __builtin_amdgcn_mfma_f32_16x16x32_f16(a3, Ub[15], d3, 0, 0, 0);      \
    float p0 = c0[0] + d0[0];                                                  \
    float p1 = c1[0] + d1[0];                                                  \
    float p2 = c2[0] + d2[0];                                                  \
    float p3 = c3[0] + d3[0];                                                  \
    float ig = hsig(p0), fg = hsig(p1), og = hsig(p3);                         \
    float gg = tanh_f(p2);                                                     \
    cst = fmaf(fg, cst, ig * gg);                                              \
    vh  = og * tanh_f(cst);                                                    \
    if (lane < 16) hlds[((T) + 1) & 1][w * 16 + lane] = __float2half(vh);      \
    {                                                                          \
      const float* xsrc = xcol + ((size_t)((T) + 2) << 14);  /* slack-backed */ \
      _Pragma("unroll")                                                        \
      for (int g = 0; g < 4; ++g) XP[g] = xsrc[g * 128];                       \
    }                                                                          \
    asm volatile("s_waitcnt lgkmcnt(0)" ::: "memory");                         \
    __builtin_amdgcn_s_barrier();                                              \
    asm volatile("" ::: "memory");                                             \
  }while(0)

  for (int t = 0; t < TT; t += 2){
    STEP(t,     xpA);
    STEP(t + 1, xpB);
  }
#undef STEP

  if (lane < 16) out[b * HH + w * 16 + lane] = vh;
}

extern "C" void kernel_launch(void* const* d_in, const int* in_sizes, int n_in,
                              void* d_out, int out_size, void* d_ws, size_t ws_size,
                              hipStream_t stream) {
  (void)in_sizes; (void)n_in; (void)out_size; (void)ws_size;

  // ---- workspace layout (~18.6 MB) ----
  // [0,16) flag | [16,528) vx | [1024,+128K) Uw | [+128K) Ww | [+2M) newx
  // [+16M) Xp fp32[8192*512] + 128KB slack (2 step-rows) for unclamped distance-2
  // prefetch (steps 254/255 read rows 256/257; values unused).
  char* ws = (char*)d_ws;
  int* flag = (int*)ws;
  float* vx = (float*)(ws + 16);
  uint4* Uw = (uint4*)(ws + 1024);
  uint4* Ww = (uint4*)(ws + 1024 + 131072);
  __half* newx = (__half*)(ws + 1024 + 2 * 131072);
  float* Xp = (float*)(ws + 1024 + 2 * 131072 + (size_t)2 * 1024 * 1024);

  k_prep<<<65, 256, 0, stream>>>(d_in[0], d_in[1],
      d_in[4], d_in[7], d_in[10], d_in[13],    // U_i, U_f, U_c, U_o
      d_in[3], d_in[6], d_in[9],  d_in[12],    // W_i, W_f, W_c, W_o
      flag, vx, Uw, Ww);
  k_pool<<<BB * TT / 2, 256, 0, stream>>>(d_in[0], flag, vx, newx);
  dim3 g2(64, 4);
  k_xproj<<<g2, 256, 0, stream>>>(newx, Ww,
      d_in[5], d_in[8], d_in[11], d_in[14],    // b_i, b_f, b_c, b_o
      flag, Xp);
  k_rec<<<BB, 512, 0, stream>>>(Xp, Uw, (float*)d_out);
}